// Round 1
// baseline (237.636 us; speedup 1.0000x reference)
//
#include <hip/hip_runtime.h>
#include <hip/hip_bf16.h>
#include <stdint.h>

#define BB   8
#define CIN  256
#define CI   128
#define NN   4096
#define EPSV 1e-5f

typedef __attribute__((ext_vector_type(8))) short bf16x8;
typedef __attribute__((ext_vector_type(4))) short bf16x4;
typedef __attribute__((ext_vector_type(4))) float f32x4;

static __device__ inline short f2bf(float f) {
    uint32_t u = __builtin_bit_cast(uint32_t, f);
    u += 0x7FFFu + ((u >> 16) & 1u);   // round-to-nearest-even
    return (short)(u >> 16);
}

// ---------------------------------------------------------------------------
// Kernel 1: BN + the three 1x1 projections (theta->Q, phi->K, g->V^T), bf16 out
// C[n][o] = sum_c BN(x[b][c][n]) * W[o][c] + bias[o]
// grid: 3 * B * (N/64); block 256 (4 waves, each wave = 16 rows of n)
// ---------------------------------------------------------------------------
__global__ __launch_bounds__(256) void proj_kernel(
    const float* __restrict__ x,
    const float* __restrict__ gamma, const float* __restrict__ beta,
    const float* __restrict__ mean,  const float* __restrict__ var,
    const float* __restrict__ wg,  const float* __restrict__ bg,
    const float* __restrict__ wth, const float* __restrict__ bth,
    const float* __restrict__ wph, const float* __restrict__ bph,
    short* __restrict__ qp, short* __restrict__ kp, short* __restrict__ vtp)
{
    __shared__ float s_scale[CIN];
    __shared__ float s_shift[CIN];
    __shared__ __align__(16) short A_lds[64][72];    // [n][c], pad 72 -> 2-way free
    __shared__ __align__(16) short B_lds[128][72];   // [o][c]

    const int tid = threadIdx.x;
    const int bid = blockIdx.x;
    const int s   = bid / (BB * 64);          // 0=theta,1=phi,2=g
    const int r   = bid % (BB * 64);
    const int b   = r / 64;
    const int n0  = (r % 64) * 64;

    {   // BN scale/shift (256 threads == 256 channels)
        float sc = gamma[tid] * rsqrtf(var[tid] + EPSV);
        s_scale[tid] = sc;
        s_shift[tid] = beta[tid] - mean[tid] * sc;
    }
    __syncthreads();

    const float* wsrc = (s == 0) ? wth : (s == 1) ? wph : wg;
    const float* bsrc = (s == 0) ? bth : (s == 1) ? bph : bg;

    const int w = tid >> 6, lane = tid & 63, lr = lane & 15, lg = lane >> 4;

    f32x4 acc[8];
    #pragma unroll
    for (int i = 0; i < 8; ++i) acc[i] = (f32x4){0.f, 0.f, 0.f, 0.f};

    for (int c0 = 0; c0 < CIN; c0 += 64) {
        // stage A: BN(x) transposed to [n][c]
        #pragma unroll
        for (int pass = 0; pass < 4; ++pass) {
            int c  = c0 + pass * 16 + (tid >> 4);
            int n4 = (tid & 15) * 4;
            f32x4 v = *(const f32x4*)&x[((size_t)b * CIN + c) * NN + n0 + n4];
            float sc = s_scale[c], sh = s_shift[c];
            #pragma unroll
            for (int i = 0; i < 4; ++i)
                A_lds[n4 + i][c - c0] = f2bf(v[i] * sc + sh);
        }
        // stage B: weights [o][c] (direct, no transpose)
        #pragma unroll
        for (int pass = 0; pass < 8; ++pass) {
            int o  = pass * 16 + (tid >> 4);
            int c4 = (tid & 15) * 4;
            f32x4 v = *(const f32x4*)&wsrc[(size_t)o * CIN + c0 + c4];
            bf16x4 bv;
            #pragma unroll
            for (int i = 0; i < 4; ++i) bv[i] = f2bf(v[i]);
            *(bf16x4*)&B_lds[o][c4] = bv;
        }
        __syncthreads();

        bf16x8 a0 = *(const bf16x8*)&A_lds[w * 16 + lr][lg * 8];
        bf16x8 a1 = *(const bf16x8*)&A_lds[w * 16 + lr][32 + lg * 8];
        #pragma unroll
        for (int ot = 0; ot < 8; ++ot) {
            bf16x8 b0 = *(const bf16x8*)&B_lds[ot * 16 + lr][lg * 8];
            bf16x8 b1 = *(const bf16x8*)&B_lds[ot * 16 + lr][32 + lg * 8];
            acc[ot] = __builtin_amdgcn_mfma_f32_16x16x32_bf16(a0, b0, acc[ot], 0, 0, 0);
            acc[ot] = __builtin_amdgcn_mfma_f32_16x16x32_bf16(a1, b1, acc[ot], 0, 0, 0);
        }
        __syncthreads();
    }

    if (s < 2) {   // Q / K: (b, n, c) row-major
        short* dst = (s == 0) ? qp : kp;
        #pragma unroll
        for (int ot = 0; ot < 8; ++ot) {
            float bias = bsrc[ot * 16 + lr];
            #pragma unroll
            for (int rr = 0; rr < 4; ++rr) {
                int n = n0 + w * 16 + lg * 4 + rr;
                dst[((size_t)b * NN + n) * CI + ot * 16 + lr] = f2bf(acc[ot][rr] + bias);
            }
        }
    } else {       // V^T: (b, c, n) — 4 consecutive n per lane -> 8B stores
        #pragma unroll
        for (int ot = 0; ot < 8; ++ot) {
            float bias = bsrc[ot * 16 + lr];
            bf16x4 pk;
            #pragma unroll
            for (int rr = 0; rr < 4; ++rr) pk[rr] = f2bf(acc[ot][rr] + bias);
            *(bf16x4*)&vtp[((size_t)b * CI + ot * 16 + lr) * NN + n0 + w * 16 + lg * 4] = pk;
        }
    }
}

// ---------------------------------------------------------------------------
// Kernel 2: flash attention, no 1/sqrt(d). QBLK=64 (4 waves x 16 rows), KVBLK=64.
// grid: B * (N/64); writes Y^T (b, n, c) bf16.
// ---------------------------------------------------------------------------
__global__ __launch_bounds__(256) void attn_kernel(
    const short* __restrict__ qp, const short* __restrict__ kp,
    const short* __restrict__ vtp, short* __restrict__ yp)
{
    __shared__ __align__(16) short K_lds[64 * 128];     // [m][c], XOR-swizzled bytes
    __shared__ __align__(16) short V_lds[128][72];      // [c][m], padded
    __shared__ __align__(16) short P_lds[4][16][72];    // per-wave P transpose

    const int tid = threadIdx.x;
    const int b  = blockIdx.x >> 6;
    const int n0 = (blockIdx.x & 63) * 64;
    const int w = tid >> 6, lane = tid & 63, lr = lane & 15, lg = lane >> 4;

    // Q strip in registers (A-frags: row = lr, k = lg*8+j contiguous)
    bf16x8 qf[4];
    {
        const short* qrow = qp + ((size_t)b * NN + n0 + w * 16 + lr) * CI;
        #pragma unroll
        for (int kf = 0; kf < 4; ++kf)
            qf[kf] = *(const bf16x8*)&qrow[kf * 32 + lg * 8];
    }

    f32x4 yacc[8];
    #pragma unroll
    for (int i = 0; i < 8; ++i) yacc[i] = (f32x4){0.f, 0.f, 0.f, 0.f};
    float m_run[4], l_run[4];
    #pragma unroll
    for (int i = 0; i < 4; ++i) { m_run[i] = -__builtin_huge_valf(); l_run[i] = 0.f; }

    for (int m0 = 0; m0 < NN; m0 += 64) {
        // stage K tile [m][c] with byte ^= ((m&7)<<4) swizzle (G4: D=128 fix)
        #pragma unroll
        for (int pass = 0; pass < 4; ++pass) {
            int mm = pass * 16 + (tid >> 4);
            int cb = (tid & 15) * 8;
            bf16x8 v = *(const bf16x8*)&kp[((size_t)b * NN + m0 + mm) * CI + cb];
            int off = mm * 256 + ((cb * 2) ^ ((mm & 7) << 4));
            *(bf16x8*)((char*)K_lds + off) = v;
        }
        // stage V tile [c][m] — V already transposed in ws, so linear copy
        #pragma unroll
        for (int pass = 0; pass < 4; ++pass) {
            int c  = pass * 32 + (tid >> 3);
            int mb = (tid & 7) * 8;
            *(bf16x8*)&V_lds[c][mb] =
                *(const bf16x8*)&vtp[((size_t)b * CI + c) * NN + m0 + mb];
        }
        __syncthreads();

        // S = Q K^T  (B-frag: col = m = lr, k = c contiguous from K_lds row)
        f32x4 sa[4];
        #pragma unroll
        for (int mt = 0; mt < 4; ++mt) sa[mt] = (f32x4){0.f, 0.f, 0.f, 0.f};
        #pragma unroll
        for (int mt = 0; mt < 4; ++mt) {
            int mrow = mt * 16 + lr;
            #pragma unroll
            for (int kf = 0; kf < 4; ++kf) {
                int cb2 = (kf * 32 + lg * 8) * 2;
                bf16x8 kfrag = *(const bf16x8*)((const char*)K_lds +
                                 mrow * 256 + (cb2 ^ ((mrow & 7) << 4)));
                sa[mt] = __builtin_amdgcn_mfma_f32_16x16x32_bf16(qf[kf], kfrag, sa[mt], 0, 0, 0);
            }
        }

        // online softmax (rows live in 16-lane groups; 4 rows/lane via reg idx)
        float pv[4][4];
        #pragma unroll
        for (int rr = 0; rr < 4; ++rr) {
            float mx = fmaxf(fmaxf(sa[0][rr], sa[1][rr]), fmaxf(sa[2][rr], sa[3][rr]));
            #pragma unroll
            for (int off = 1; off < 16; off <<= 1)
                mx = fmaxf(mx, __shfl_xor(mx, off));
            float mnew  = fmaxf(m_run[rr], mx);
            float scale = __expf(m_run[rr] - mnew);
            float rs = 0.f;
            #pragma unroll
            for (int mt = 0; mt < 4; ++mt) {
                float e = __expf(sa[mt][rr] - mnew);
                pv[mt][rr] = e;
                rs += e;
            }
            #pragma unroll
            for (int off = 1; off < 16; off <<= 1)
                rs += __shfl_xor(rs, off);
            l_run[rr] = l_run[rr] * scale + rs;
            m_run[rr] = mnew;
            #pragma unroll
            for (int ct = 0; ct < 8; ++ct) yacc[ct][rr] *= scale;
        }

        // P: C-layout -> A-layout via per-wave LDS (stride 72 => 2-way free)
        #pragma unroll
        for (int mt = 0; mt < 4; ++mt)
            #pragma unroll
            for (int rr = 0; rr < 4; ++rr)
                P_lds[w][lg * 4 + rr][mt * 16 + lr] = f2bf(pv[mt][rr]);
        asm volatile("" ::: "memory");   // order ds_write -> ds_read (DS in-order/wave)

        // Y += P V   (B-frag from V_lds[c][m]: k = m contiguous)
        #pragma unroll
        for (int kf = 0; kf < 2; ++kf) {
            bf16x8 pa = *(const bf16x8*)&P_lds[w][lr][kf * 32 + lg * 8];
            #pragma unroll
            for (int ct = 0; ct < 8; ++ct) {
                bf16x8 vf = *(const bf16x8*)&V_lds[ct * 16 + lr][kf * 32 + lg * 8];
                yacc[ct] = __builtin_amdgcn_mfma_f32_16x16x32_bf16(pa, vf, yacc[ct], 0, 0, 0);
            }
        }
        __syncthreads();
    }

    // normalize + store Y^T (b, n, c)
    #pragma unroll
    for (int ct = 0; ct < 8; ++ct) {
        #pragma unroll
        for (int rr = 0; rr < 4; ++rr) {
            int n = n0 + w * 16 + lg * 4 + rr;
            yp[((size_t)b * NN + n) * CI + ct * 16 + lr] =
                f2bf(yacc[ct][rr] / l_run[rr]);
        }
    }
}

// ---------------------------------------------------------------------------
// Kernel 3: out = w_w @ Y + b_w + x.  M=o (coalesced n-stores), 128x128 tiles.
// grid: 2 * B * (N/128)
// ---------------------------------------------------------------------------
__global__ __launch_bounds__(256) void out_kernel(
    const short* __restrict__ yp, const float* __restrict__ ww,
    const float* __restrict__ bw, const float* __restrict__ x,
    float* __restrict__ out)
{
    __shared__ __align__(16) short A_lds[128][136];   // w_w [o][c]
    __shared__ __align__(16) short Bl[128][136];      // Y^T [n][c]

    const int tid = threadIdx.x;
    const int ob = blockIdx.x & 1;
    const int g  = blockIdx.x >> 1;
    const int b  = g >> 5;
    const int nn = (g & 31) * 128;
    const int o0 = ob * 128;
    const int w = tid >> 6, lane = tid & 63, lr = lane & 15, lg = lane >> 4;

    #pragma unroll
    for (int pass = 0; pass < 8; ++pass) {
        int o  = pass * 16 + (tid >> 4);
        int c8 = (tid & 15) * 8;
        f32x4 v0 = *(const f32x4*)&ww[(size_t)(o0 + o) * CI + c8];
        f32x4 v1 = *(const f32x4*)&ww[(size_t)(o0 + o) * CI + c8 + 4];
        bf16x8 bv;
        #pragma unroll
        for (int i = 0; i < 4; ++i) { bv[i] = f2bf(v0[i]); bv[4 + i] = f2bf(v1[i]); }
        *(bf16x8*)&A_lds[o][c8] = bv;
    }
    #pragma unroll
    for (int pass = 0; pass < 8; ++pass) {
        int n  = pass * 16 + (tid >> 4);
        int c8 = (tid & 15) * 8;
        *(bf16x8*)&Bl[n][c8] = *(const bf16x8*)&yp[((size_t)b * NN + nn + n) * CI + c8];
    }
    __syncthreads();

    f32x4 acc[2][8];
    #pragma unroll
    for (int i = 0; i < 2; ++i)
        #pragma unroll
        for (int j = 0; j < 8; ++j) acc[i][j] = (f32x4){0.f, 0.f, 0.f, 0.f};

    #pragma unroll
    for (int kf = 0; kf < 4; ++kf) {
        bf16x8 a0 = *(const bf16x8*)&A_lds[w * 32 + lr][kf * 32 + lg * 8];
        bf16x8 a1 = *(const bf16x8*)&A_lds[w * 32 + 16 + lr][kf * 32 + lg * 8];
        #pragma unroll
        for (int nt = 0; nt < 8; ++nt) {
            bf16x8 bv = *(const bf16x8*)&Bl[nt * 16 + lr][kf * 32 + lg * 8];
            acc[0][nt] = __builtin_amdgcn_mfma_f32_16x16x32_bf16(a0, bv, acc[0][nt], 0, 0, 0);
            acc[1][nt] = __builtin_amdgcn_mfma_f32_16x16x32_bf16(a1, bv, acc[1][nt], 0, 0, 0);
        }
    }

    #pragma unroll
    for (int wo = 0; wo < 2; ++wo) {
        #pragma unroll
        for (int rr = 0; rr < 4; ++rr) {
            int o = o0 + w * 32 + wo * 16 + lg * 4 + rr;
            float bias = bw[o];
            #pragma unroll
            for (int nt = 0; nt < 8; ++nt) {
                size_t idx = ((size_t)b * CIN + o) * NN + nn + nt * 16 + lr;
                out[idx] = acc[wo][nt][rr] + bias + x[idx];
            }
        }
    }
}

// ---------------------------------------------------------------------------
extern "C" void kernel_launch(void* const* d_in, const int* in_sizes, int n_in,
                              void* d_out, int out_size, void* d_ws, size_t ws_size,
                              hipStream_t stream)
{
    const float* x     = (const float*)d_in[0];
    const float* gamma = (const float*)d_in[1];
    const float* beta  = (const float*)d_in[2];
    const float* mean  = (const float*)d_in[3];
    const float* var   = (const float*)d_in[4];
    const float* wg    = (const float*)d_in[5];
    const float* bg    = (const float*)d_in[6];
    const float* wth   = (const float*)d_in[7];
    const float* bth   = (const float*)d_in[8];
    const float* wph   = (const float*)d_in[9];
    const float* bph   = (const float*)d_in[10];
    const float* ww    = (const float*)d_in[11];
    const float* bw    = (const float*)d_in[12];

    // workspace: Q, K (b,n,c) + V^T (b,c,n) + Y^T (b,n,c), bf16: 4 x 8 MiB = 32 MiB
    const size_t seg = (size_t)BB * NN * CI;
    short* qp  = (short*)d_ws;
    short* kp  = qp + seg;
    short* vtp = kp + seg;
    short* yp  = vtp + seg;
    (void)in_sizes; (void)n_in; (void)out_size; (void)ws_size;

    proj_kernel<<<3 * BB * (NN / 64), 256, 0, stream>>>(
        x, gamma, beta, mean, var, wg, bg, wth, bth, wph, bph, qp, kp, vtp);
    attn_kernel<<<BB * (NN / 64), 256, 0, stream>>>(qp, kp, vtp, yp);
    out_kernel<<<2 * BB * (NN / 128), 256, 0, stream>>>(yp, ww, bw, x, (float*)d_out);
}

// Round 2
// 182.528 us; speedup vs baseline: 1.3019x; 1.3019x over previous
//
#include <hip/hip_runtime.h>
#include <hip/hip_bf16.h>
#include <stdint.h>

#define BB   8
#define CIN  256
#define CI   128
#define NN   4096
#define EPSV 1e-5f
#define LOG2E 1.44269504088896340736f

typedef __attribute__((ext_vector_type(8))) short bf16x8;
typedef __attribute__((ext_vector_type(4))) short bf16x4;
typedef __attribute__((ext_vector_type(4))) float f32x4;

static __device__ inline short f2bf(float f) {
    uint32_t u = __builtin_bit_cast(uint32_t, f);
    u += 0x7FFFu + ((u >> 16) & 1u);   // round-to-nearest-even
    return (short)(u >> 16);
}

// ---------------------------------------------------------------------------
// Kernel 1: BN + the three 1x1 projections (theta->Q, phi->K, g->V^T), bf16 out
// Q (theta) is pre-scaled by log2(e) so attn can use raw v_exp_f32 (exp2).
// ---------------------------------------------------------------------------
__global__ __launch_bounds__(256) void proj_kernel(
    const float* __restrict__ x,
    const float* __restrict__ gamma, const float* __restrict__ beta,
    const float* __restrict__ mean,  const float* __restrict__ var,
    const float* __restrict__ wg,  const float* __restrict__ bg,
    const float* __restrict__ wth, const float* __restrict__ bth,
    const float* __restrict__ wph, const float* __restrict__ bph,
    short* __restrict__ qp, short* __restrict__ kp, short* __restrict__ vtp)
{
    __shared__ float s_scale[CIN];
    __shared__ float s_shift[CIN];
    __shared__ __align__(16) short A_lds[64][72];    // [n][c], pad 72 -> 2-way free
    __shared__ __align__(16) short B_lds[128][72];   // [o][c]

    const int tid = threadIdx.x;
    const int bid = blockIdx.x;
    const int s   = bid / (BB * 64);          // 0=theta,1=phi,2=g
    const int r   = bid % (BB * 64);
    const int b   = r / 64;
    const int n0  = (r % 64) * 64;

    {   // BN scale/shift (256 threads == 256 channels)
        float sc = gamma[tid] * rsqrtf(var[tid] + EPSV);
        s_scale[tid] = sc;
        s_shift[tid] = beta[tid] - mean[tid] * sc;
    }
    __syncthreads();

    const float* wsrc = (s == 0) ? wth : (s == 1) ? wph : wg;
    const float* bsrc = (s == 0) ? bth : (s == 1) ? bph : bg;

    const int w = tid >> 6, lane = tid & 63, lr = lane & 15, lg = lane >> 4;

    f32x4 acc[8];
    #pragma unroll
    for (int i = 0; i < 8; ++i) acc[i] = (f32x4){0.f, 0.f, 0.f, 0.f};

    for (int c0 = 0; c0 < CIN; c0 += 64) {
        // stage A: BN(x) transposed to [n][c]
        #pragma unroll
        for (int pass = 0; pass < 4; ++pass) {
            int c  = c0 + pass * 16 + (tid >> 4);
            int n4 = (tid & 15) * 4;
            f32x4 v = *(const f32x4*)&x[((size_t)b * CIN + c) * NN + n0 + n4];
            float sc = s_scale[c], sh = s_shift[c];
            #pragma unroll
            for (int i = 0; i < 4; ++i)
                A_lds[n4 + i][c - c0] = f2bf(v[i] * sc + sh);
        }
        // stage B: weights [o][c]
        #pragma unroll
        for (int pass = 0; pass < 8; ++pass) {
            int o  = pass * 16 + (tid >> 4);
            int c4 = (tid & 15) * 4;
            f32x4 v = *(const f32x4*)&wsrc[(size_t)o * CIN + c0 + c4];
            bf16x4 bv;
            #pragma unroll
            for (int i = 0; i < 4; ++i) bv[i] = f2bf(v[i]);
            *(bf16x4*)&B_lds[o][c4] = bv;
        }
        __syncthreads();

        bf16x8 a0 = *(const bf16x8*)&A_lds[w * 16 + lr][lg * 8];
        bf16x8 a1 = *(const bf16x8*)&A_lds[w * 16 + lr][32 + lg * 8];
        #pragma unroll
        for (int ot = 0; ot < 8; ++ot) {
            bf16x8 b0 = *(const bf16x8*)&B_lds[ot * 16 + lr][lg * 8];
            bf16x8 b1 = *(const bf16x8*)&B_lds[ot * 16 + lr][32 + lg * 8];
            acc[ot] = __builtin_amdgcn_mfma_f32_16x16x32_bf16(a0, b0, acc[ot], 0, 0, 0);
            acc[ot] = __builtin_amdgcn_mfma_f32_16x16x32_bf16(a1, b1, acc[ot], 0, 0, 0);
        }
        __syncthreads();
    }

    if (s < 2) {   // Q / K: (b, n, c) row-major; Q scaled by log2e
        short* dst = (s == 0) ? qp : kp;
        const float om = (s == 0) ? LOG2E : 1.0f;
        #pragma unroll
        for (int ot = 0; ot < 8; ++ot) {
            float bias = bsrc[ot * 16 + lr];
            #pragma unroll
            for (int rr = 0; rr < 4; ++rr) {
                int n = n0 + w * 16 + lg * 4 + rr;
                dst[((size_t)b * NN + n) * CI + ot * 16 + lr] = f2bf((acc[ot][rr] + bias) * om);
            }
        }
    } else {       // V^T: (b, c, n)
        #pragma unroll
        for (int ot = 0; ot < 8; ++ot) {
            float bias = bsrc[ot * 16 + lr];
            bf16x4 pk;
            #pragma unroll
            for (int rr = 0; rr < 4; ++rr) pk[rr] = f2bf(acc[ot][rr] + bias);
            *(bf16x4*)&vtp[((size_t)b * CI + ot * 16 + lr) * NN + n0 + w * 16 + lg * 4] = pk;
        }
    }
}

// ---------------------------------------------------------------------------
// Kernel 2: flash attention. Swapped QK^T (in-register softmax), double-buffered
// K/V staged via global_load_lds w/ pre-swizzled source (linear LDS dest),
// XOR swizzle byte^=((row&7)<<4) on both K and V reads. One barrier per iter.
// grid: B * (N/64); 4 waves; writes Y^T (b, n, c) bf16.
// ---------------------------------------------------------------------------
__global__ __launch_bounds__(256) void attn_kernel(
    const short* __restrict__ qp, const short* __restrict__ kp,
    const short* __restrict__ vtp, short* __restrict__ yp)
{
    __shared__ __align__(16) char K_sh[2][64 * 256];    // [m][c] swizzled, 16KB x2
    __shared__ __align__(16) char V_sh[2][128 * 128];   // [c][m] swizzled, 16KB x2
    __shared__ __align__(16) short P_lds[4][16][72];    // per-wave P[q][m], pad 72

    const int tid = threadIdx.x;
    const int b   = blockIdx.x >> 6;
    const int n0  = (blockIdx.x & 63) * 64;
    const int w = tid >> 6, lane = tid & 63, lr = lane & 15, lg = lane >> 4;

    const short* kbatch = kp  + (size_t)b * NN * CI;
    const short* vbatch = vtp + (size_t)b * CI * NN;

    // stage K/V tile t into buffer bufi: linear LDS dest, inverse-swizzled source
    auto stage = [&](int bufi, int t) {
        const short* ksrc = kbatch + (size_t)t * 64 * CI;
        const short* vsrc = vbatch + (size_t)t * 64;
        #pragma unroll
        for (int r = 0; r < 4; ++r) {
            int idx = ((r * 4 + w) << 6) + lane;          // 16B-chunk index 0..1023
            int mm  = idx >> 4, cb = (idx & 15) << 4;     // K: row m, dest col-byte
            const char* gk = (const char*)(ksrc + (size_t)mm * CI) + (cb ^ ((mm & 7) << 4));
            __builtin_amdgcn_global_load_lds(
                (const __attribute__((address_space(1))) void*)gk,
                (__attribute__((address_space(3))) void*)&K_sh[bufi][(r * 4 + w) << 10],
                16, 0, 0);
            int cc = idx >> 3, cbv = (idx & 7) << 4;      // V: row c, dest col-byte
            const char* gv = (const char*)(vsrc + (size_t)cc * NN) + (cbv ^ ((cc & 7) << 4));
            __builtin_amdgcn_global_load_lds(
                (const __attribute__((address_space(1))) void*)gv,
                (__attribute__((address_space(3))) void*)&V_sh[bufi][(r * 4 + w) << 10],
                16, 0, 0);
        }
    };

    // Q strip in registers (identical indexing serves as B-frag for mfma(K,Q))
    bf16x8 qf[4];
    {
        const short* qrow = qp + ((size_t)b * NN + n0 + w * 16 + lr) * CI;
        #pragma unroll
        for (int kf = 0; kf < 4; ++kf)
            qf[kf] = *(const bf16x8*)&qrow[kf * 32 + lg * 8];
    }

    f32x4 yacc[8];
    #pragma unroll
    for (int i = 0; i < 8; ++i) yacc[i] = (f32x4){0.f, 0.f, 0.f, 0.f};
    float m_run = -__builtin_huge_valf(), l_run = 0.f;

    stage(0, 0);
    __syncthreads();

    for (int t = 0; t < NN / 64; ++t) {
        const int cur = t & 1;
        if (t + 1 < NN / 64) stage(cur ^ 1, t + 1);   // issue before compute

        // S^T = K Q : D[m][q], lane (lr,lg) holds S[q=lr][m=mt*16+lg*4+rr]
        const char* Kc = K_sh[cur];
        f32x4 sa[4];
        __builtin_amdgcn_s_setprio(1);
        #pragma unroll
        for (int mt = 0; mt < 4; ++mt) {
            const int mrow = mt * 16 + lr;
            const int sw   = (mrow & 7) << 4;
            sa[mt] = (f32x4){0.f, 0.f, 0.f, 0.f};
            #pragma unroll
            for (int kf = 0; kf < 4; ++kf) {
                bf16x8 kfrag = *(const bf16x8*)(Kc + (mrow << 8) + ((kf * 64 + lg * 16) ^ sw));
                sa[mt] = __builtin_amdgcn_mfma_f32_16x16x32_bf16(kfrag, qf[kf], sa[mt], 0, 0, 0);
            }
        }
        __builtin_amdgcn_s_setprio(0);

        // in-register online softmax for row q=lr (values are log2-scaled)
        float tm = fmaxf(fmaxf(fmaxf(sa[0][0], sa[0][1]), fmaxf(sa[0][2], sa[0][3])),
                         fmaxf(fmaxf(sa[1][0], sa[1][1]), fmaxf(sa[1][2], sa[1][3])));
        tm = fmaxf(tm, fmaxf(fmaxf(fmaxf(sa[2][0], sa[2][1]), fmaxf(sa[2][2], sa[2][3])),
                             fmaxf(fmaxf(sa[3][0], sa[3][1]), fmaxf(sa[3][2], sa[3][3]))));
        tm = fmaxf(tm, __shfl_xor(tm, 16));
        tm = fmaxf(tm, __shfl_xor(tm, 32));
        float mnew  = fmaxf(m_run, tm);
        float scale = __builtin_amdgcn_exp2f(m_run - mnew);
        m_run = mnew;
        float rs = 0.f;
        #pragma unroll
        for (int mt = 0; mt < 4; ++mt) {
            bf16x4 pk;
            #pragma unroll
            for (int rr = 0; rr < 4; ++rr) {
                float e = __builtin_amdgcn_exp2f(sa[mt][rr] - mnew);
                rs += e;
                pk[rr] = f2bf(e);
            }
            *(bf16x4*)&P_lds[w][lr][mt * 16 + lg * 4] = pk;   // packed 8B write
        }
        rs += __shfl_xor(rs, 16);
        rs += __shfl_xor(rs, 32);
        l_run = l_run * scale + rs;

        // rescale yacc rows (yacc row q = lg*4+rr; scale lives at lane lr=q)
        #pragma unroll
        for (int rr = 0; rr < 4; ++rr) {
            float sc = __shfl(scale, (lane & 48) | (lg * 4 + rr));
            #pragma unroll
            for (int ct = 0; ct < 8; ++ct) yacc[ct][rr] *= sc;
        }

        asm volatile("" ::: "memory");   // order P_lds write -> read

        // Y += P V
        const char* Vc = V_sh[cur];
        __builtin_amdgcn_s_setprio(1);
        #pragma unroll
        for (int kf = 0; kf < 2; ++kf) {
            bf16x8 pa = *(const bf16x8*)&P_lds[w][lr][kf * 32 + lg * 8];
            #pragma unroll
            for (int ct = 0; ct < 8; ++ct) {
                const int vr = ct * 16 + lr;
                bf16x8 vf = *(const bf16x8*)(Vc + (vr << 7) +
                                             ((kf * 64 + lg * 16) ^ ((vr & 7) << 4)));
                yacc[ct] = __builtin_amdgcn_mfma_f32_16x16x32_bf16(pa, vf, yacc[ct], 0, 0, 0);
            }
        }
        __builtin_amdgcn_s_setprio(0);

        __syncthreads();   // drains vmcnt: next tile staged; buf[cur] reads done
    }

    // normalize + store Y^T (b, n, c): yacc[ct][rr] = Y[q=lg*4+rr][c=ct*16+lr]
    #pragma unroll
    for (int rr = 0; rr < 4; ++rr) {
        float li  = __shfl(l_run, (lane & 48) | (lg * 4 + rr));
        float inv = 1.0f / li;
        int n = n0 + w * 16 + lg * 4 + rr;
        #pragma unroll
        for (int ct = 0; ct < 8; ++ct)
            yp[((size_t)b * NN + n) * CI + ct * 16 + lr] = f2bf(yacc[ct][rr] * inv);
    }
}

// ---------------------------------------------------------------------------
// Kernel 3: out = w_w @ Y + b_w + x.  M=o (coalesced n-stores), 128x128 tiles.
// ---------------------------------------------------------------------------
__global__ __launch_bounds__(256) void out_kernel(
    const short* __restrict__ yp, const float* __restrict__ ww,
    const float* __restrict__ bw, const float* __restrict__ x,
    float* __restrict__ out)
{
    __shared__ __align__(16) short A_lds[128][136];   // w_w [o][c]
    __shared__ __align__(16) short Bl[128][136];      // Y^T [n][c]

    const int tid = threadIdx.x;
    const int ob = blockIdx.x & 1;
    const int g  = blockIdx.x >> 1;
    const int b  = g >> 5;
    const int nn = (g & 31) * 128;
    const int o0 = ob * 128;
    const int w = tid >> 6, lane = tid & 63, lr = lane & 15, lg = lane >> 4;

    #pragma unroll
    for (int pass = 0; pass < 8; ++pass) {
        int o  = pass * 16 + (tid >> 4);
        int c8 = (tid & 15) * 8;
        f32x4 v0 = *(const f32x4*)&ww[(size_t)(o0 + o) * CI + c8];
        f32x4 v1 = *(const f32x4*)&ww[(size_t)(o0 + o) * CI + c8 + 4];
        bf16x8 bv;
        #pragma unroll
        for (int i = 0; i < 4; ++i) { bv[i] = f2bf(v0[i]); bv[4 + i] = f2bf(v1[i]); }
        *(bf16x8*)&A_lds[o][c8] = bv;
    }
    #pragma unroll
    for (int pass = 0; pass < 8; ++pass) {
        int n  = pass * 16 + (tid >> 4);
        int c8 = (tid & 15) * 8;
        *(bf16x8*)&Bl[n][c8] = *(const bf16x8*)&yp[((size_t)b * NN + nn + n) * CI + c8];
    }
    __syncthreads();

    f32x4 acc[2][8];
    #pragma unroll
    for (int i = 0; i < 2; ++i)
        #pragma unroll
        for (int j = 0; j < 8; ++j) acc[i][j] = (f32x4){0.f, 0.f, 0.f, 0.f};

    #pragma unroll
    for (int kf = 0; kf < 4; ++kf) {
        bf16x8 a0 = *(const bf16x8*)&A_lds[w * 32 + lr][kf * 32 + lg * 8];
        bf16x8 a1 = *(const bf16x8*)&A_lds[w * 32 + 16 + lr][kf * 32 + lg * 8];
        #pragma unroll
        for (int nt = 0; nt < 8; ++nt) {
            bf16x8 bv = *(const bf16x8*)&Bl[nt * 16 + lr][kf * 32 + lg * 8];
            acc[0][nt] = __builtin_amdgcn_mfma_f32_16x16x32_bf16(a0, bv, acc[0][nt], 0, 0, 0);
            acc[1][nt] = __builtin_amdgcn_mfma_f32_16x16x32_bf16(a1, bv, acc[1][nt], 0, 0, 0);
        }
    }

    #pragma unroll
    for (int wo = 0; wo < 2; ++wo) {
        #pragma unroll
        for (int rr = 0; rr < 4; ++rr) {
            int o = o0 + w * 32 + wo * 16 + lg * 4 + rr;
            float bias = bw[o];
            #pragma unroll
            for (int nt = 0; nt < 8; ++nt) {
                size_t idx = ((size_t)b * CIN + o) * NN + nn + nt * 16 + lr;
                out[idx] = acc[wo][nt][rr] + bias + x[idx];
            }
        }
    }
}

// ---------------------------------------------------------------------------
extern "C" void kernel_launch(void* const* d_in, const int* in_sizes, int n_in,
                              void* d_out, int out_size, void* d_ws, size_t ws_size,
                              hipStream_t stream)
{
    const float* x     = (const float*)d_in[0];
    const float* gamma = (const float*)d_in[1];
    const float* beta  = (const float*)d_in[2];
    const float* mean  = (const float*)d_in[3];
    const float* var   = (const float*)d_in[4];
    const float* wg    = (const float*)d_in[5];
    const float* bg    = (const float*)d_in[6];
    const float* wth   = (const float*)d_in[7];
    const float* bth   = (const float*)d_in[8];
    const float* wph   = (const float*)d_in[9];
    const float* bph   = (const float*)d_in[10];
    const float* ww    = (const float*)d_in[11];
    const float* bw    = (const float*)d_in[12];

    const size_t seg = (size_t)BB * NN * CI;
    short* qp  = (short*)d_ws;
    short* kp  = qp + seg;
    short* vtp = kp + seg;
    short* yp  = vtp + seg;
    (void)in_sizes; (void)n_in; (void)out_size; (void)ws_size;

    proj_kernel<<<3 * BB * (NN / 64), 256, 0, stream>>>(
        x, gamma, beta, mean, var, wg, bg, wth, bth, wph, bph, qp, kp, vtp);
    attn_kernel<<<BB * (NN / 64), 256, 0, stream>>>(qp, kp, vtp, yp);
    out_kernel<<<2 * BB * (NN / 128), 256, 0, stream>>>(yp, ww, bw, x, (float*)d_out);
}